// Round 7
// baseline (240.270 us; speedup 1.0000x reference)
//
#include <hip/hip_runtime.h>
#include <math.h>

#define NCLS 10
#define NB   16
#define NG   60
#define NA   33600          // 160*160 + 80*80 + 40*40
#define BA   (NB*NA)        // 537600
#define NW   4              // waves per topk1 block
#define NSPL 4              // topk1 grid split
#define NLIST (NSPL*NW)     // 16 sorted lists per (b,g)
#define NBLK_X 132          // ceil(NA/256)
#define NBLK_LOSS (NBLK_X*NB)

// ---- static device scratch (load-time zero; self-restoring across calls) ----
__device__ double g_part[NBLK_LOSS][4];     // per-loss-block partials (nfg, iou, obj, cls)
__device__ int    g_fcount[NB];             // fg count per image (reset by final_kernel)
__device__ int    g_nmatch[BA];             // all-zero between calls (self-cleaned by loss)
__device__ int    g_gsum[BA];               // all-zero between calls (self-cleaned by loss)
__device__ int    g_slot[BA];               // compact slot (valid for fg anchors only)
// compacted per-image fg-anchor data
__device__ float4 g_cbox [BA];              // [b][j] bx,by,bw,bh
__device__ float4 g_cmeta[BA];              // [b][j] xc, yc, S, anchor_id_bits
__device__ float  g_cD   [(size_t)NB*NCLS*NA];  // [b][c][j] class-major
// per-(b,g,split,wave) sorted top-10 lists
__device__ unsigned long long s_kv [(size_t)NB*NG*NLIST*10];
__device__ float              s_iou[(size_t)NB*NG*NLIST*10];

__device__ __forceinline__ void anchor_geom(int a, int& H, int& W, float& s, int& h, int& w, int& lvl) {
  if (a < 25600)      { lvl = 0; H = 160; W = 160; s = 8.f;  h = a / 160;            w = a - h*160; }
  else if (a < 32000) { lvl = 1; H = 80;  W = 80;  s = 16.f; int r = a - 25600; h = r / 80;  w = r - h*80; }
  else                { lvl = 2; H = 40;  W = 40;  s = 32.f; int r = a - 32000; h = r / 40;  w = r - h*40; }
}

// monotone float->uint key (order-preserving for all finite floats)
__device__ __forceinline__ unsigned int fkey(float f) {
  unsigned int b = __float_as_uint(f);
  return (b & 0x80000000u) ? ~b : (b | 0x80000000u);
}

// ---- Kernel A: y-band GT filter -> fg test -> compact -> decode planes (fg only) ----
__global__ __launch_bounds__(256) void decode_kernel(const float* __restrict__ p0,
                                                     const float* __restrict__ p1,
                                                     const float* __restrict__ p2,
                                                     const float* __restrict__ lb) {
  __shared__ float lab[NG*5];
  __shared__ int   glist[NG];
  __shared__ int   gln;
  __shared__ int   wbase[4];
  __shared__ int   bbase_s;
  int b = blockIdx.y, tid = threadIdx.x;
  for (int i = tid; i < NG*5; i += 256) lab[i] = lb[(size_t)b*NG*5 + i];
  if (tid == 0) gln = 0;
  __syncthreads();

  // block anchor-band geometry (blocks never straddle levels: 25600, 32000 are 256-aligned)
  int a0 = blockIdx.x * 256;
  int H, W, h0, w0, lvl; float st;
  anchor_geom(a0, H, W, st, h0, w0, lvl);
  int aL = a0 + 255; if (aL >= NA) aL = NA - 1;
  int H2, W2, h1, w2, l2; float st2;
  anchor_geom(aL, H2, W2, st2, h1, w2, l2);
  float ylo = ((float)h0 + 0.5f) * st;
  float yhi = ((float)h1 + 0.5f) * st;
  float rad = 2.5f * st;

  // per-GT y-band relevance filter (conservative)
  if (tid < NG) {
    float s0 = lab[tid*5] + lab[tid*5+1] + lab[tid*5+2] + lab[tid*5+3] + lab[tid*5+4];
    if (s0 > 0.f) {
      float gy = lab[tid*5+2], gh = lab[tid*5+4];
      float m = fmaxf(gh * 0.5f, rad);
      if ((gy - m < yhi) && (gy + m > ylo)) {
        int p = atomicAdd(&gln, 1);
        glist[p] = tid;
      }
    }
  }
  __syncthreads();

  int a = a0 + tid;
  bool valid = a < NA;
  int n = gln;

  float xc = 0.f, yc = 0.f;
  int fg = 0;
  if (valid && n > 0) {
    int h = h0 + (a0 + tid) / W - a0 / W;          // cheap row advance within block
    int w = a - h * W - (lvl == 0 ? 0 : (lvl == 1 ? 25600 - h*0 : 0)); // recompute safely below
    // (recompute plainly to avoid subtle index math)
    int Ht, Wt, ht, wt, lt; float stt;
    anchor_geom(a, Ht, Wt, stt, ht, wt, lt);
    xc = ((float)wt + 0.5f) * st;
    yc = ((float)ht + 0.5f) * st;
    for (int q = 0; q < n; q++) {
      int g = glist[q];
      float gx = lab[g*5+1], gy = lab[g*5+2], gw = lab[g*5+3], gh = lab[g*5+4];
      float l  = xc - (gx - gw*0.5f);
      float r  = (gx + gw*0.5f) - xc;
      float t  = yc - (gy - gh*0.5f);
      float bo = (gy + gh*0.5f) - yc;
      float m1 = fminf(fminf(l, r), fminf(t, bo));
      float cl = xc - gx + rad, cr = gx + rad - xc, ct = yc - gy + rad, cb = gy + rad - yc;
      float m2 = fminf(fminf(cl, cr), fminf(ct, cb));
      if (m1 > 0.f || m2 > 0.f) { fg = 1; break; }
    }
  }

  // block-aggregated compaction: one atomic per block
  unsigned long long m = __ballot(fg != 0);
  int lane = tid & 63, wv = tid >> 6;
  if (lane == 0) wbase[wv] = __popcll(m);
  __syncthreads();
  if (tid == 0) {
    int t = 0;
    #pragma unroll
    for (int k = 0; k < 4; k++) { int c = wbase[k]; wbase[k] = t; t += c; }
    bbase_s = t ? atomicAdd(&g_fcount[b], t) : 0;
  }
  __syncthreads();

  if (fg) {
    int Ht, Wt, ht, wt, lt; float stt;
    anchor_geom(a, Ht, Wt, stt, ht, wt, lt);
    const float* pp = (lvl == 0) ? p0 : ((lvl == 1) ? p1 : p2);
    size_t cs = (size_t)H * W;
    size_t base = (size_t)b * 15 * cs + (size_t)ht * W + wt;

    float tx = pp[base], ty = pp[base+cs], tw = pp[base+2*cs], th = pp[base+3*cs], to = pp[base+4*cs];
    float4 boxv = make_float4((tx + (float)wt) * st, (ty + (float)ht) * st,
                              __expf(tw) * st, __expf(th) * st);

    float so = 1.f / (1.f + __expf(-to));
    float S = 0.f;
    float Dl[NCLS];
    #pragma unroll
    for (int c = 0; c < NCLS; c++) {
      float xl = pp[base + (size_t)(5 + c) * cs];
      float sc = 1.f / (1.f + __expf(-xl));
      float p  = sqrtf(sc * so);
      float L  = __logf(p + 1e-12f);
      float M  = __logf(1.f - p + 1e-12f);
      S += M;
      Dl[c] = L - M;
    }

    int j = bbase_s + wbase[wv] + (int)__popcll(m & ((1ULL << lane) - 1ULL));
    size_t cb = (size_t)b * NA + j;
    g_cbox[cb]  = boxv;
    g_cmeta[cb] = make_float4(xc, yc, S, __int_as_float(a));
    #pragma unroll
    for (int c = 0; c < NCLS; c++) g_cD[((size_t)b*NCLS + c)*NA + j] = Dl[c];
    g_slot[b * NA + a] = j;
  }
}

// ---- Kernel B1: per-(b,g,split) striped scan of compacted fg anchors ----
__global__ __launch_bounds__(256) void topk1_kernel(const float* __restrict__ lb) {
  int fid = blockIdx.x;                 // XCD-clustering remap: images {2r,2r+1} -> XCD r
  int sp  = blockIdx.y;
  int t8 = fid >> 3;
  int b  = ((fid & 7) << 1) + (t8 >= 60 ? 1 : 0);
  int g  = t8 - (t8 >= 60 ? 60 : 0);
  int tid = threadIdx.x, lane = tid & 63, wv = tid >> 6;

  const float* L = &lb[((size_t)b*NG + g)*5];
  float l0 = L[0], l1 = L[1], l2 = L[2], l3 = L[3], l4 = L[4];
  if (!(l0 + l1 + l2 + l3 + l4 > 0.f)) return;

  int   gc = (int)l0;
  float gx = l1, gy = l2, gw = l3, gh = l4;
  float a1x = gx - gw*0.5f, a1y = gy - gh*0.5f, a2x = gx + gw*0.5f, a2y = gy + gh*0.5f;
  float garea = gw * gh;
  int F = g_fcount[b];
  const float4* CB = &g_cbox [(size_t)b*NA];
  const float4* CM = &g_cmeta[(size_t)b*NA];
  const float*  CD = &g_cD[((size_t)b*NCLS + gc)*NA];

  unsigned long long kv[10]; float iv[10];
  #pragma unroll
  for (int k = 0; k < 10; k++) { kv[k] = ~0ULL; iv[k] = 0.f; }

  for (int j = sp * 256 + tid; j < F; j += NSPL * 256) {
    float4 B = CB[j];
    float4 M = CM[j];
    float Dv = CD[j];
    int a = __float_as_int(M.w);
    float b1x = B.x - B.z*0.5f, b1y = B.y - B.w*0.5f;
    float b2x = B.x + B.z*0.5f, b2y = B.y + B.w*0.5f;
    float wx = fminf(a2x, b2x) - fmaxf(a1x, b1x); wx = wx > 0.f ? wx : 0.f;
    float wy = fminf(a2y, b2y) - fmaxf(a1y, b1y); wy = wy > 0.f ? wy : 0.f;
    float inter = wx * wy;
    float iou = inter / (garea + B.z*B.w - inter + 1e-8f);
    float xc = M.x, yc = M.y;
    float rad = (a < 25600) ? 20.f : ((a < 32000) ? 40.f : 80.f);
    bool inb = fminf(fminf(xc - a1x, a2x - xc), fminf(yc - a1y, a2y - yc)) > 0.f;
    bool inc = fminf(fminf(xc - gx + rad, gx + rad - xc), fminf(yc - gy + rad, gy + rad - yc)) > 0.f;
    float cost = -(Dv + M.z) + 3.0f * (-__logf(iou + 1e-8f));
    if (!(inb && inc)) cost += 100000.0f;

    unsigned long long key = ((unsigned long long)fkey(cost) << 32) | (unsigned int)a;
    if (key < kv[9]) {
      kv[9] = key;
      #pragma unroll
      for (int k = 9; k > 0; k--) {
        if (kv[k] < kv[k-1]) { unsigned long long t = kv[k]; kv[k] = kv[k-1]; kv[k-1] = t; }
      }
    }
    if (iou > iv[9]) {
      iv[9] = iou;
      #pragma unroll
      for (int k = 9; k > 0; k--) {
        if (iv[k] > iv[k-1]) { float t = iv[k]; iv[k] = iv[k-1]; iv[k-1] = t; }
      }
    }
  }

  // wave-level extraction merge -> sorted top-10 per (split,wave) list
  size_t slot = ((((size_t)b*NG + g)*NSPL + sp)*NW + wv) * 10;
  for (int k = 0; k < 10; k++) {
    unsigned long long m = kv[0];
    #pragma unroll
    for (int d = 1; d < 64; d <<= 1) {
      unsigned long long o = __shfl_xor(m, d);
      if (o < m) m = o;
    }
    if (m == ~0ULL) {        // exhausted: pad
      if (lane == 0) for (int k2 = k; k2 < 10; k2++) s_kv[slot+k2] = ~0ULL;
      break;
    }
    if (lane == 0) s_kv[slot+k] = m;
    if (kv[0] == m) {        // unique key -> exactly one lane pops
      #pragma unroll
      for (int j2 = 0; j2 < 9; j2++) kv[j2] = kv[j2+1];
      kv[9] = ~0ULL;
    }
  }
  for (int k = 0; k < 10; k++) {
    float m = iv[0];
    #pragma unroll
    for (int d = 1; d < 64; d <<= 1) m = fmaxf(m, __shfl_xor(m, d));
    if (m <= 0.f) {          // rest are zeros
      if (lane == 0) for (int k2 = k; k2 < 10; k2++) s_iou[slot+k2] = 0.f;
      break;
    }
    if (lane == 0) s_iou[slot+k] = m;
    unsigned long long pm = __ballot(iv[0] == m);
    if (lane == __ffsll((unsigned long long)pm) - 1) {
      #pragma unroll
      for (int j2 = 0; j2 < 9; j2++) iv[j2] = iv[j2+1];
      iv[9] = 0.f;
    }
  }
}

// ---- Kernel B2: merge NLIST sorted lists per (b,g), dyn_k, scatter matches ----
__global__ __launch_bounds__(64) void topk2_kernel(const float* __restrict__ lb) {
  int t = blockIdx.x * 64 + threadIdx.x;
  if (t >= NB * NG) return;
  int b = t / NG, g = t - b * NG;
  const float* L = &lb[(size_t)t * 5];
  if (!(L[0] + L[1] + L[2] + L[3] + L[4] > 0.f)) return;

  size_t base = (size_t)t * (NLIST*10);
  unsigned long long kv[10]; float iv[10];
  #pragma unroll
  for (int k = 0; k < 10; k++) { kv[k] = s_kv[base+k]; iv[k] = s_iou[base+k]; }

  for (int l = 1; l < NLIST; l++) {
    size_t o = base + (size_t)l*10;
    #pragma unroll
    for (int k = 0; k < 10; k++) {
      unsigned long long key = s_kv[o+k];
      if (key < kv[9]) {
        kv[9] = key;
        #pragma unroll
        for (int k2 = 9; k2 > 0; k2--) {
          if (kv[k2] < kv[k2-1]) { unsigned long long tt = kv[k2]; kv[k2] = kv[k2-1]; kv[k2-1] = tt; }
        }
      } else break;          // source sorted ascending
    }
    #pragma unroll
    for (int k = 0; k < 10; k++) {
      float w = s_iou[o+k];
      if (w > iv[9]) {
        iv[9] = w;
        #pragma unroll
        for (int k2 = 9; k2 > 0; k2--) {
          if (iv[k2] > iv[k2-1]) { float tv = iv[k2]; iv[k2] = iv[k2-1]; iv[k2-1] = tv; }
        }
      } else break;          // source sorted descending
    }
  }

  float ss = 0.f;
  #pragma unroll
  for (int k = 0; k < 10; k++) ss += iv[k];   // descending order, same sum order as ref
  int dynk = (int)ss;
  if (dynk < 1)  dynk = 1;
  if (dynk > 10) dynk = 10;
  for (int k = 0; k < dynk; k++) {
    if (kv[k] == ~0ULL) break;                 // defensive
    int a = (int)(unsigned int)(kv[k] & 0xFFFFFFFFu);
    atomicAdd(&g_nmatch[b*NA + a], 1);
    atomicAdd(&g_gsum[b*NA + a], g);
  }
}

// ---- Kernel C: dedup (argmin over g), per-anchor losses, per-block partial store ----
__global__ __launch_bounds__(256) void loss_kernel(const float* __restrict__ p0,
                                                   const float* __restrict__ p1,
                                                   const float* __restrict__ p2,
                                                   const float* __restrict__ lb) {
  __shared__ float  lab[NG*5];
  __shared__ int    lval[NG];
  __shared__ double red[256*4];
  int b = blockIdx.y, tid = threadIdx.x;
  for (int i = tid; i < NG*5; i += 256) lab[i] = lb[(size_t)b*NG*5 + i];
  __syncthreads();
  if (tid < NG) {
    float s = lab[tid*5] + lab[tid*5+1] + lab[tid*5+2] + lab[tid*5+3] + lab[tid*5+4];
    lval[tid] = (s > 0.f) ? 1 : 0;
  }
  __syncthreads();

  int a = blockIdx.x * 256 + tid;
  double t_nfg = 0.0, t_iou = 0.0, t_obj = 0.0, t_cls = 0.0;

  if (a < NA) {
    int idx = b * NA + a;
    int H, W, h, w, lvl; float st;
    anchor_geom(a, H, W, st, h, w, lvl);
    const float* pp = (lvl == 0) ? p0 : ((lvl == 1) ? p1 : p2);
    size_t cs = (size_t)H * W;
    size_t base = (size_t)b * 15 * cs + (size_t)h * W + w;

    float x  = pp[base + 4*cs];
    int   nm = g_nmatch[idx];
    float t  = (nm > 0) ? 1.f : 0.f;
    float bce = fmaxf(x, 0.f) - x * t + log1pf(expf(-fabsf(x)));
    float pr  = 1.f / (1.f + expf(-x));
    float pt  = (nm > 0) ? pr : (1.f - pr);
    float wf  = (nm > 0) ? 0.25f : 0.75f;
    float om  = 1.f - pt;
    t_obj = (double)(bce * wf * om * om);

    if (nm > 0) {
      t_nfg = 1.0;
      int mgsum = g_gsum[idx];
      g_nmatch[idx] = 0;           // self-clean for next call
      g_gsum[idx]   = 0;
      int j = g_slot[idx];
      float4 B  = g_cbox [(size_t)b*NA + j];
      float4 Mt = g_cmeta[(size_t)b*NA + j];
      float pw = B.z, ph = B.w;
      float b1x = B.x - pw*0.5f, b1y = B.y - ph*0.5f, b2x = B.x + pw*0.5f, b2y = B.y + ph*0.5f;
      int mg;
      if (nm == 1) {
        mg = mgsum;
      } else {
        // matched => fg, so the 1e6 term reduces to validity only
        float xc = Mt.x, yc = Mt.y, S = Mt.z;
        float rad = 2.5f * st;
        const float* CDb = &g_cD[(size_t)b*NCLS*NA];
        float best = INFINITY; int bg = 0;
        for (int g = 0; g < NG; g++) {
          float gx = lab[g*5+1], gy = lab[g*5+2], gw = lab[g*5+3], gh = lab[g*5+4];
          int gcl = (int)lab[g*5];
          int v = lval[g];
          float a1x = gx - gw*0.5f, a1y = gy - gh*0.5f, a2x = gx + gw*0.5f, a2y = gy + gh*0.5f;
          float wx = fminf(a2x, b2x) - fmaxf(a1x, b1x); wx = wx > 0.f ? wx : 0.f;
          float wy = fminf(a2y, b2y) - fmaxf(a1y, b1y); wy = wy > 0.f ? wy : 0.f;
          float inter = wx * wy;
          float iou = inter / (gw*gh + pw*ph - inter + 1e-8f);
          float l = xc - a1x, r = a2x - xc, tt = yc - a1y, bo = a2y - yc;
          bool inb = (fminf(fminf(l, r), fminf(tt, bo)) > 0.f) && v;
          float cl = xc - gx + rad, cr = gx + rad - xc, ct = yc - gy + rad, cb = gy + rad - yc;
          bool inc = (fminf(fminf(cl, cr), fminf(ct, cb)) > 0.f) && v;
          float clsc = -(CDb[(size_t)gcl*NA + j] + S);
          float cost = clsc + 3.0f * (-__logf(iou + 1e-8f));
          if (!(inb && inc)) cost += 100000.0f;
          if (!v)            cost += 1000000.0f;
          if (cost < best) { best = cost; bg = g; }   // strict < : first-index tie-break
        }
        mg = bg;
      }

      float gx = lab[mg*5+1], gy = lab[mg*5+2], gw = lab[mg*5+3], gh = lab[mg*5+4];
      int mcls = (int)lab[mg*5];
      float a1x = gx - gw*0.5f, a1y = gy - gh*0.5f, a2x = gx + gw*0.5f, a2y = gy + gh*0.5f;
      float wx = fminf(a2x, b2x) - fmaxf(a1x, b1x); wx = wx > 0.f ? wx : 0.f;
      float wy = fminf(a2y, b2y) - fmaxf(a1y, b1y); wy = wy > 0.f ? wy : 0.f;
      float inter = wx * wy;
      float miou = inter / (gw*gh + pw*ph - inter + 1e-8f);  // == forward-loss IoU bit-exact

      t_iou = (double)(1.f - miou * miou);

      float sc = 0.f;
      #pragma unroll
      for (int c = 0; c < NCLS; c++) {
        float xl = pp[base + (size_t)(5 + c) * cs];
        float ctg = (c == mcls) ? miou : 0.f;
        sc += fmaxf(xl, 0.f) - xl * ctg + log1pf(expf(-fabsf(xl)));
      }
      t_cls = (double)sc;
    }
  }

  red[tid] = t_nfg; red[256+tid] = t_iou; red[512+tid] = t_obj; red[768+tid] = t_cls;
  __syncthreads();
  for (int s = 128; s > 0; s >>= 1) {
    if (tid < s) {
      red[tid]     += red[tid+s];
      red[256+tid] += red[256+tid+s];
      red[512+tid] += red[512+tid+s];
      red[768+tid] += red[768+tid+s];
    }
    __syncthreads();
  }
  if (tid == 0) {
    int blk = b * NBLK_X + blockIdx.x;
    g_part[blk][0] = red[0];
    g_part[blk][1] = red[256];
    g_part[blk][2] = red[512];
    g_part[blk][3] = red[768];
  }
}

// ---- Kernel D: reduce per-block partials, finalize, reset fcount ----
__global__ __launch_bounds__(256) void final_kernel(float* __restrict__ out) {
  __shared__ double red[256];
  int tid = threadIdx.x;
  int cat = tid & 3;
  double s = 0.0;
  for (int blk = tid >> 2; blk < NBLK_LOSS; blk += 64) s += g_part[blk][cat];
  red[tid] = s;
  __syncthreads();
  for (int st = 128; st >= 4; st >>= 1) {
    if (tid < st) red[tid] += red[tid + st];
    __syncthreads();
  }
  if (tid == 0) {
    double nfg = red[0];
    double num = (nfg < 1.0) ? 1.0 : nfg;
    float li = (float)(red[1] / num);
    float lo = (float)(red[2] / num);
    float lc = (float)(red[3] / num);
    out[0] = 5.0f * li + lo;   // REG_W * loss_iou + loss_obj
    out[1] = li;
    out[2] = lo;
    out[3] = lc;
  }
  if (tid < NB) g_fcount[tid] = 0;   // self-restore for next call
}

extern "C" void kernel_launch(void* const* d_in, const int* in_sizes, int n_in,
                              void* d_out, int out_size, void* d_ws, size_t ws_size,
                              hipStream_t stream) {
  const float* p0 = (const float*)d_in[0];
  const float* p1 = (const float*)d_in[1];
  const float* p2 = (const float*)d_in[2];
  const float* lb = (const float*)d_in[3];
  float* out = (float*)d_out;

  hipLaunchKernelGGL(decode_kernel, dim3(NBLK_X, NB), dim3(256), 0, stream, p0, p1, p2, lb);
  hipLaunchKernelGGL(topk1_kernel,  dim3(NB*NG, NSPL), dim3(256), 0, stream, lb);
  hipLaunchKernelGGL(topk2_kernel,  dim3((NB*NG + 63) / 64), dim3(64), 0, stream, lb);
  hipLaunchKernelGGL(loss_kernel,   dim3(NBLK_X, NB), dim3(256), 0, stream, p0, p1, p2, lb);
  hipLaunchKernelGGL(final_kernel,  dim3(1), dim3(256), 0, stream, out);
}